// Round 12
// baseline (277.934 us; speedup 1.0000x reference)
//
#include <hip/hip_runtime.h>

// ---- problem constants ----
#define NIN 64
#define NOPS 1024
#define NB 2048
#define NNODES 1088            // NIN + NOPS
#define SLAB_SH 18             // node slot stride = 2048 rows * 128 B = 1<<18

// ---- workspace layout (bytes) ----
#define WS_SCHED 0u            // u64[1024] packed ops, sorted by (level, mat)
#define WS_LEV   8192u         // u32: [0]=nlev, [1]=slot of node 1087, [2]=err; +4096: u16 msta[2048]
#define WS_WT    16384u        // f16[8][64][128]  ([mat][n][k]), one-input mats zero-padded k>=64
#define WS_BIAS  147456u       // f32[512]
#define WS_NODES 163840u       // f16[cap][2048][64] slot slabs

typedef unsigned int u32;
typedef unsigned short u16;
typedef unsigned long long u64;
typedef _Float16 f16;
typedef _Float16 f16x8 __attribute__((ext_vector_type(8)));
typedef _Float16 f16x4 __attribute__((ext_vector_type(4)));
typedef float f32x4 __attribute__((ext_vector_type(4)));

#define MFMA16(a, b, c) __builtin_amdgcn_mfma_f32_16x16x32_f16((a), (b), (c), 0, 0, 0)

// sched word bits (only 0-10 slot1 | 11-21 slot2 | 25-35 outslot used by k_main)

// ---------------- schedule: levels + (level,mat) sort + liveness slot allocation ----------------
__global__ __launch_bounds__(1024) void k_sched(const int* __restrict__ wxv,
                                                const int* __restrict__ in1v,
                                                const int* __restrict__ in2v,
                                                char* __restrict__ ws, int cap) {
  __shared__ int s1[NOPS], s2[NOPS], sw[NOPS], slv[NOPS];
  __shared__ int lcnt[132];
  __shared__ int cnt2[1032];
  __shared__ u64 s_pack[NOPS];
  __shared__ int dl[NNODES], slot_of[NNODES], stk[NNODES];
  __shared__ int s_flag, s_nlev, s_top, s_next;
  const int j = threadIdx.x;
  s1[j] = in1v[j]; s2[j] = in2v[j]; sw[j] = wxv[j]; slv[j] = 1;
  if (j < 132) lcnt[j] = 0;
  if (j < 1032) cnt2[j] = 0;
  __syncthreads();
  // monotone relaxation: lvl[j] = 1 + max(lvl(parents)); one-input ops depend only on in1
  for (int it = 0; it < NOPS + 1; ++it) {
    if (j == 0) s_flag = 0;
    __syncthreads();
    int p1 = s1[j];
    int l1 = (p1 >= NIN) ? slv[p1 - NIN] : 0;
    int l2 = 0;
    if (sw[j] >= 4) { int p2 = s2[j]; l2 = (p2 >= NIN) ? slv[p2 - NIN] : 0; }
    int nl = 1 + (l1 > l2 ? l1 : l2);
    if (nl != slv[j]) { slv[j] = nl; s_flag = 1; }
    __syncthreads();
    int f = s_flag;
    __syncthreads();
    if (!f) break;
  }
  if (j == 0) s_nlev = 0;
  __syncthreads();
  atomicMax(&s_nlev, slv[j]);
  __syncthreads();
  u32* wl = (u32*)(ws + WS_LEV);
  const int nlev = s_nlev;
  if (nlev > 127) { if (j == 0) { wl[0] = 0; wl[1] = 0; wl[2] = 1; } return; }
  atomicAdd(&lcnt[slv[j]], 1);
  atomicAdd(&cnt2[slv[j] * 8 + sw[j]], 1);
  __syncthreads();
  if (j == 0) {
    int acc = 0;
    for (int L = 1; L <= nlev; ++L) { int c = lcnt[L]; lcnt[L] = acc; acc += c; }  // level bases
  }
  __syncthreads();
  int base = -1;
  if (j >= 8 && j < (nlev + 1) * 8) {
    int L = j >> 3, mm = j & 7;
    int s = lcnt[L];
    for (int q = 0; q < mm; ++q) s += cnt2[L * 8 + q];
    base = s;
  }
  u16* msta = (u16*)(ws + WS_LEV + 4096);
  for (int t = j; t < 2048; t += 1024) msta[t] = (u16)NOPS;
  __syncthreads();
  if (base >= 0) { cnt2[j] = base; msta[j] = (u16)base; }   // cnt2 becomes the cursor
  __syncthreads();
  { int slot = atomicAdd(&cnt2[slv[j] * 8 + sw[j]], 1);
    u64 p = (u64)(u32)s1[j] | ((u64)(u32)s2[j] << 11) | ((u64)(u32)sw[j] << 22) | ((u64)(u32)j << 25);
    s_pack[slot] = p; }
  // death levels
  for (int t = j; t < NNODES; t += 1024) dl[t] = (t < NIN) ? 0 : slv[t - NIN];
  __syncthreads();
  atomicMax(&dl[s1[j]], slv[j]);
  if (sw[j] >= 4) atomicMax(&dl[s2[j]], slv[j]);
  __syncthreads();
  if (j == 0) { dl[NNODES - 1] = nlev + 1; s_top = 0; s_next = NIN; }
  if (j < NIN) slot_of[j] = j;
  __syncthreads();
  // greedy interval-coloring by level: free (dl == L-1) then allocate (slv == L)
  for (int L = 1; L <= nlev; ++L) {
    for (int t = j; t < NNODES; t += 1024)
      if (dl[t] == L - 1) { int p = atomicAdd(&s_top, 1); stk[p] = slot_of[t]; }
    __syncthreads();
    if (slv[j] == L) {
      int p = atomicSub(&s_top, 1);
      int s;
      if (p >= 1) s = stk[p - 1]; else s = atomicAdd(&s_next, 1);
      slot_of[NIN + j] = s;
    }
    __syncthreads();
    if (j == 0 && s_top < 0) s_top = 0;
    __syncthreads();
  }
  // rewrite schedule entries with slot indices
  {
    u64 m = s_pack[j];
    int i1n = (int)(m & 2047u), i2n = (int)((m >> 11) & 2047u);
    u32 wxn = (u32)((m >> 22) & 7u);
    int opn = (int)((m >> 25) & 2047u);
    if (wxn < 4) i2n = i1n;           // one-input: i2:=i1 (guaranteed-live slot)
    u32 s1slot = (u32)slot_of[i1n];
    u32 s2slot = (u32)slot_of[i2n];
    u64 nm = (u64)s1slot | ((u64)s2slot << 11) | ((u64)wxn << 22)
           | ((u64)(u32)slot_of[NIN + opn] << 25);
    ((u64*)(ws + WS_SCHED))[j] = nm;
  }
  if (j == 0) {
    wl[0] = (u32)nlev;
    wl[1] = (u32)slot_of[NNODES - 1];
    wl[2] = (s_next > cap) ? 1u : 0u;
  }
}

// ---------------- weights: unify + zero-pad + transpose to [mat][n][k], fp16 ----------------
__global__ __launch_bounds__(256) void k_weights(const float* __restrict__ oW,
                                                 const float* __restrict__ ob,
                                                 const float* __restrict__ tW,
                                                 const float* __restrict__ tb,
                                                 char* __restrict__ ws) {
  f16* wt = (f16*)(ws + WS_WT);
  int t = blockIdx.x * 256 + threadIdx.x;
  #pragma unroll
  for (int q = 0; q < 4; ++q) {
    int e = t * 4 + q;                       // e = mat*8192 + n*128 + k
    int mat = e >> 13, n = (e >> 7) & 63, k = e & 127;
    float v;
    if (mat < 4) v = (k < 64) ? oW[mat * 4096 + k * 64 + n] : 0.f;
    else         v = tW[(mat - 4) * 8192 + k * 64 + n];
    wt[e] = (f16)v;
  }
  if (blockIdx.x == 0) {
    float* bs = (float*)(ws + WS_BIAS);
    for (int q = threadIdx.x; q < 512; q += 256)
      bs[q] = (q < 256) ? ob[q] : tb[q - 256];
  }
}

// ---------------- leaves: embedding gather -> slots 0..63 (fp16, vectorized) ----------------
__global__ __launch_bounds__(256) void k_leaves(const int* __restrict__ ids,
                                                const float* __restrict__ emb,
                                                char* __restrict__ ws) {
  int p = blockIdx.x * 256 + threadIdx.x;      // 131072 (i,b) pairs
  int i = p >> 11, b = p & 2047;
  int id = ids[b * 64 + i];
  const f32x4* src = (const f32x4*)(emb + (u32)id * 64u);
  f16x8* dst = (f16x8*)(ws + WS_NODES + ((u32)i << SLAB_SH) + (u32)b * 128u);
  #pragma unroll
  for (int q = 0; q < 8; ++q) {
    f32x4 lo = src[2 * q], hi = src[2 * q + 1];
    f16x8 v = { (f16)lo.x, (f16)lo.y, (f16)lo.z, (f16)lo.w,
                (f16)hi.x, (f16)hi.y, (f16)hi.z, (f16)hi.w };
    dst[q] = v;
  }
}

// ---------------- main: mat waves, all-global, chunked single-assignment batch loads ----------------
__global__ __launch_bounds__(1024, 4) void k_main(char* __restrict__ ws) {
  __shared__ u64 s_sched[NOPS];   // 8 KB
  __shared__ u16 s_msta[2048];    // 4 KB
  const int tid = threadIdx.x;
  const u32* wl = (const u32*)(ws + WS_LEV);
  if (wl[2]) return;               // uniform early-out before any barrier
  s_sched[tid] = ((const u64*)(ws + WS_SCHED))[tid];
  ((u32*)s_msta)[tid] = ((const u32*)(ws + WS_LEV + 4096))[tid & 1023];
  const int nlev = (int)wl[0];

  const int lane = tid & 63;
  const int w   = tid >> 6;        // 16 waves
  const int m   = w & 7;           // owned weight matrix (m<4 => one-input)
  const int nh  = w >> 3;          // column half
  const int lhi = lane >> 4, llo = lane & 15;
  const int r0  = blockIdx.x * 8;  // 256 blocks x 8 batch rows
  char* nodes = ws + WS_NODES;

  // W cache: (32 cols x 128 k) slice of mat m; one-input waves only k<64 half
  const f16* wp = (const f16*)(ws + WS_WT) + m * 8192 + (nh * 32 + llo) * 128 + lhi * 8;
  const f16x8 W00 = *(const f16x8*)(wp +        0), W01 = *(const f16x8*)(wp +       32),
              W10 = *(const f16x8*)(wp + 2048 + 0), W11 = *(const f16x8*)(wp + 2048 + 32);
  f16x8 W02 = {}, W03 = {}, W12 = {}, W13 = {};
  if (m >= 4) {
    W02 = *(const f16x8*)(wp +       64); W03 = *(const f16x8*)(wp +       96);
    W12 = *(const f16x8*)(wp + 2048 + 64); W13 = *(const f16x8*)(wp + 2048 + 96);
  }
  const float* bsp = (const float*)(ws + WS_BIAS) + m * 64 + nh * 32 + lhi * 4;
  const f32x4 B0 = *(const f32x4*)(bsp), B1 = *(const f32x4*)(bsp + 16);
  __syncthreads();

  const u32 a_off  = (u32)((r0 + (llo & 7)) * 128 + lhi * 16);
  const u32 st_off = (u32)((r0 + llo) * 128 + (nh * 32 + lhi * 4) * 2);

  auto load1 = [&](u64 md, f16x8& a0, f16x8& a1) {
    const char* b1 = nodes + ((u64)((u32)md & 2047u) << SLAB_SH) + a_off;
    a0 = *(const f16x8*)(b1);
    a1 = *(const f16x8*)(b1 + 64);
  };
  auto load2 = [&](u64 md, f16x8& a2, f16x8& a3) {
    const char* b2 = nodes + ((u64)(((u32)(md >> 11)) & 2047u) << SLAB_SH) + a_off;
    a2 = *(const f16x8*)(b2);
    a3 = *(const f16x8*)(b2 + 64);
  };
  auto compT = [&](u64 md, const f16x8& a0, const f16x8& a1,
                   const f16x8& a2, const f16x8& a3) {
    f32x4 c0 = B0, c1 = B1;
    __builtin_amdgcn_s_setprio(1);
    c0 = MFMA16(W00, a0, c0); c0 = MFMA16(W01, a1, c0);
    c0 = MFMA16(W02, a2, c0); c0 = MFMA16(W03, a3, c0);
    c1 = MFMA16(W10, a0, c1); c1 = MFMA16(W11, a1, c1);
    c1 = MFMA16(W12, a2, c1); c1 = MFMA16(W13, a3, c1);
    __builtin_amdgcn_s_setprio(0);
    f16x4 r0v = { (f16)(c0.x > 0.f ? c0.x : 0.f), (f16)(c0.y > 0.f ? c0.y : 0.f),
                  (f16)(c0.z > 0.f ? c0.z : 0.f), (f16)(c0.w > 0.f ? c0.w : 0.f) };
    f16x4 r1v = { (f16)(c1.x > 0.f ? c1.x : 0.f), (f16)(c1.y > 0.f ? c1.y : 0.f),
                  (f16)(c1.z > 0.f ? c1.z : 0.f), (f16)(c1.w > 0.f ? c1.w : 0.f) };
    if (llo < 8) {
      char* st = nodes + (((u64)((md >> 25) & 2047u)) << SLAB_SH) + st_off;
      *(f16x4*)(st)      = r0v;
      *(f16x4*)(st + 32) = r1v;
    }
  };
  auto compO = [&](u64 md, const f16x8& a0, const f16x8& a1) {
    f32x4 c0 = B0, c1 = B1;
    __builtin_amdgcn_s_setprio(1);
    c0 = MFMA16(W00, a0, c0); c0 = MFMA16(W01, a1, c0);
    c1 = MFMA16(W10, a0, c1); c1 = MFMA16(W11, a1, c1);
    __builtin_amdgcn_s_setprio(0);
    f16x4 r0v = { (f16)(c0.x > 0.f ? c0.x : 0.f), (f16)(c0.y > 0.f ? c0.y : 0.f),
                  (f16)(c0.z > 0.f ? c0.z : 0.f), (f16)(c0.w > 0.f ? c0.w : 0.f) };
    f16x4 r1v = { (f16)(c1.x > 0.f ? c1.x : 0.f), (f16)(c1.y > 0.f ? c1.y : 0.f),
                  (f16)(c1.z > 0.f ? c1.z : 0.f), (f16)(c1.w > 0.f ? c1.w : 0.f) };
    if (llo < 8) {
      char* st = nodes + (((u64)((md >> 25) & 2047u)) << SLAB_SH) + st_off;
      *(f16x4*)(st)      = r0v;
      *(f16x4*)(st + 32) = r1v;
    }
  };

  for (int L = 1; L <= nlev; ++L) {
    int k0 = (int)s_msta[L * 8 + m];
    int k1 = (int)s_msta[L * 8 + m + 1];
    k0 = __builtin_amdgcn_readfirstlane(k0);
    k1 = __builtin_amdgcn_readfirstlane(k1);
    if (m < 4) {
      // one-input: chunks of 6, 12 independent loads, single-assignment regs
      for (int base = k0; base < k1; base += 6) {
        const int ke = k1 - 1;
        int j1 = base + 1 > ke ? ke : base + 1;
        int j2 = base + 2 > ke ? ke : base + 2;
        int j3 = base + 3 > ke ? ke : base + 3;
        int j4 = base + 4 > ke ? ke : base + 4;
        int j5 = base + 5 > ke ? ke : base + 5;
        u64 m0 = s_sched[base], m1 = s_sched[j1], m2 = s_sched[j2],
            m3 = s_sched[j3],   m4 = s_sched[j4], m5 = s_sched[j5];
        f16x8 a00, a01, a10, a11, a20, a21, a30, a31, a40, a41, a50, a51;
        load1(m0, a00, a01); load1(m1, a10, a11); load1(m2, a20, a21);
        load1(m3, a30, a31); load1(m4, a40, a41); load1(m5, a50, a51);
        __builtin_amdgcn_sched_barrier(0);     // pin batch issue above consumes
        compO(m0, a00, a01);
        if (base + 1 < k1) compO(m1, a10, a11);
        if (base + 2 < k1) compO(m2, a20, a21);
        if (base + 3 < k1) compO(m3, a30, a31);
        if (base + 4 < k1) compO(m4, a40, a41);
        if (base + 5 < k1) compO(m5, a50, a51);
      }
    } else {
      // two-input: chunks of 3, 12 independent loads
      for (int base = k0; base < k1; base += 3) {
        const int ke = k1 - 1;
        int j1 = base + 1 > ke ? ke : base + 1;
        int j2 = base + 2 > ke ? ke : base + 2;
        u64 m0 = s_sched[base], m1 = s_sched[j1], m2 = s_sched[j2];
        f16x8 a00, a01, a02, a03, a10, a11, a12, a13, a20, a21, a22, a23;
        load1(m0, a00, a01); load2(m0, a02, a03);
        load1(m1, a10, a11); load2(m1, a12, a13);
        load1(m2, a20, a21); load2(m2, a22, a23);
        __builtin_amdgcn_sched_barrier(0);
        compT(m0, a00, a01, a02, a03);
        if (base + 1 < k1) compT(m1, a10, a11, a12, a13);
        if (base + 2 < k1) compT(m2, a20, a21, a22, a23);
      }
    }
    __syncthreads();   // level boundary: drains stores (L2-visible), orders RAW
  }
}

// ---------------- final: out[b] = nodes[slot1087][b] . final_W + final_b ----------------
__global__ __launch_bounds__(256) void k_final(const float* __restrict__ fw,
                                               const float* __restrict__ fb,
                                               const char* __restrict__ ws,
                                               float* __restrict__ out) {
  __shared__ float s_fw[64];
  int t = threadIdx.x;
  if (t < 64) s_fw[t] = fw[t];
  __syncthreads();
  int b = blockIdx.x * 256 + t;
  const u32* wl = (const u32*)(ws + WS_LEV);
  if (wl[2]) { out[b] = 0.f; return; }
  u32 slot = wl[1];
  const f16x8* last = (const f16x8*)(ws + WS_NODES + ((u64)slot << SLAB_SH) + (u32)b * 128u);
  float acc = fb[0];
  #pragma unroll
  for (int q = 0; q < 8; ++q) {
    f16x8 v = last[q];
    #pragma unroll
    for (int e = 0; e < 8; ++e) acc += (float)v[e] * s_fw[q * 8 + e];
  }
  out[b] = acc;
}

extern "C" void kernel_launch(void* const* d_in, const int* in_sizes, int n_in,
                              void* d_out, int out_size, void* d_ws, size_t ws_size,
                              hipStream_t stream) {
  const int*   ids = (const int*)d_in[0];
  const int*   wx  = (const int*)d_in[1];
  const int*   i1  = (const int*)d_in[2];
  const int*   i2  = (const int*)d_in[3];
  const float* emb = (const float*)d_in[4];
  const float* oW  = (const float*)d_in[5];
  const float* ob  = (const float*)d_in[6];
  const float* tW  = (const float*)d_in[7];
  const float* tb  = (const float*)d_in[8];
  const float* fw  = (const float*)d_in[9];
  const float* fb  = (const float*)d_in[10];
  char* ws = (char*)d_ws;
  float* out = (float*)d_out;

  int cap = (int)((ws_size > (size_t)WS_NODES) ? ((ws_size - WS_NODES) >> SLAB_SH) : 0);
  if (cap < 80) return;
  if (cap > 2047) cap = 2047;

  hipLaunchKernelGGL(k_sched,   dim3(1),   dim3(1024), 0, stream, wx, i1, i2, ws, cap);
  hipLaunchKernelGGL(k_weights, dim3(64),  dim3(256),  0, stream, oW, ob, tW, tb, ws);
  hipLaunchKernelGGL(k_leaves,  dim3(512), dim3(256),  0, stream, ids, emb, ws);
  hipLaunchKernelGGL(k_main,    dim3(256), dim3(1024), 0, stream, ws);
  hipLaunchKernelGGL(k_final,   dim3(8),   dim3(256),  0, stream, fw, fb, ws, out);
}